// Round 1
// baseline (1332.991 us; speedup 1.0000x reference)
//
#include <hip/hip_runtime.h>
#include <cstdint>
#include <cstddef>

// Problem constants (match reference)
#define CNU 500000      // num users (item id offset)
#define CB  65536       // batch
#define CE  128         // embedding dim
#define CF  172         // feature dim
#define KTOT 556        // 428 (msg) + 128 (h) fused K
#define LDSW 36         // LDS row stride (floats): 16B-aligned float4 at col eg*4

// ws layout (floats): WUT[556][384] | WIT[556][384] | GWT[256][128] | PWT[128][128]
#define WUT_OFF 0
#define WIT_OFF (556*384)
#define GWT_OFF (2*556*384)
#define PWT_OFF (2*556*384 + 256*128)

__device__ __forceinline__ float sigmoidf_(float x) {
  return 1.0f / (1.0f + __expf(-x));
}

struct __align__(16) LdsBufs {
  float XC[556][LDSW];   // rows 0-127: pu, 128-255: pi, 256-427: feat, 428-555: ou
  float OIT[128][LDSW];  // oi (transposed)
  float NT[128][LDSW];   // qu -> nu_pre -> ni_pre (reused)
};

// One GRU (S=gi+gh GEMM over K=556, hn side-accum, elementwise, gate GEMM, output).
// Mapping: gg = lane gate col (0..63), thread owns gates {gg+64m}, eg selects 4 events.
template<bool SWAP>
__device__ __forceinline__ void gru_phase(
    LdsBufs& s,
    const float* __restrict__ WT,     // [556][384] transposed combined weights
    const float* __restrict__ bih,
    const float* __restrict__ bhh,
    const float* __restrict__ GWT,    // [256][128]
    const float* __restrict__ gate_b,
    const float (*HT)[LDSW],          // h transposed [128][LDSW]
    float* __restrict__ outp,         // d_out section + e0*CE
    int eg, int gg)
{
  const int ecol = eg * 4;
  float sacc[6][4];
  float hacc[2][4];
#pragma unroll
  for (int m = 0; m < 6; ++m) {
    const float b = bih[gg + 64*m] + bhh[gg + 64*m];
#pragma unroll
    for (int e4 = 0; e4 < 4; ++e4) sacc[m][e4] = b;
  }
  {
    const float b0 = bhh[256 + gg], b1 = bhh[256 + gg + 64];
#pragma unroll
    for (int e4 = 0; e4 < 4; ++e4) { hacc[0][e4] = b0; hacc[1][e4] = b1; }
  }

  // ---- S GEMM, msg part (K = 0..427), x from XC (row-remapped for item) ----
#pragma unroll 4
  for (int kk = 0; kk < 428; ++kk) {
    int r = kk;
    if (SWAP) r = (kk < 128) ? kk + 128 : ((kk < 256) ? kk - 128 : kk);
    const float4 x = *(const float4*)&s.XC[r][ecol];           // wave-uniform broadcast
    const float* w = WT + kk*384 + gg;
    const float w0 = w[0], w1 = w[64], w2 = w[128], w3 = w[192], w4 = w[256], w5 = w[320];
    sacc[0][0] += w0*x.x; sacc[0][1] += w0*x.y; sacc[0][2] += w0*x.z; sacc[0][3] += w0*x.w;
    sacc[1][0] += w1*x.x; sacc[1][1] += w1*x.y; sacc[1][2] += w1*x.z; sacc[1][3] += w1*x.w;
    sacc[2][0] += w2*x.x; sacc[2][1] += w2*x.y; sacc[2][2] += w2*x.z; sacc[2][3] += w2*x.w;
    sacc[3][0] += w3*x.x; sacc[3][1] += w3*x.y; sacc[3][2] += w3*x.z; sacc[3][3] += w3*x.w;
    sacc[4][0] += w4*x.x; sacc[4][1] += w4*x.y; sacc[4][2] += w4*x.z; sacc[4][3] += w4*x.w;
    sacc[5][0] += w5*x.x; sacc[5][1] += w5*x.y; sacc[5][2] += w5*x.z; sacc[5][3] += w5*x.w;
  }
  // ---- S GEMM, h part (K = 428..555), also accumulate hn with same weights ----
#pragma unroll 4
  for (int kk = 0; kk < 128; ++kk) {
    const float4 x = *(const float4*)&HT[kk][ecol];
    const float* w = WT + (428 + kk)*384 + gg;
    const float w0 = w[0], w1 = w[64], w2 = w[128], w3 = w[192], w4 = w[256], w5 = w[320];
    sacc[0][0] += w0*x.x; sacc[0][1] += w0*x.y; sacc[0][2] += w0*x.z; sacc[0][3] += w0*x.w;
    sacc[1][0] += w1*x.x; sacc[1][1] += w1*x.y; sacc[1][2] += w1*x.z; sacc[1][3] += w1*x.w;
    sacc[2][0] += w2*x.x; sacc[2][1] += w2*x.y; sacc[2][2] += w2*x.z; sacc[2][3] += w2*x.w;
    sacc[3][0] += w3*x.x; sacc[3][1] += w3*x.y; sacc[3][2] += w3*x.z; sacc[3][3] += w3*x.w;
    sacc[4][0] += w4*x.x; sacc[4][1] += w4*x.y; sacc[4][2] += w4*x.z; sacc[4][3] += w4*x.w;
    sacc[5][0] += w5*x.x; sacc[5][1] += w5*x.y; sacc[5][2] += w5*x.z; sacc[5][3] += w5*x.w;
    hacc[0][0] += w4*x.x; hacc[0][1] += w4*x.y; hacc[0][2] += w4*x.z; hacc[0][3] += w4*x.w;
    hacc[1][0] += w5*x.x; hacc[1][1] += w5*x.y; hacc[1][2] += w5*x.z; hacc[1][3] += w5*x.w;
  }

  __syncthreads();  // all prior readers of NT (pred / previous gate) are done

  // ---- GRU elementwise: r,z,n -> nu_pre into NT ----
#pragma unroll
  for (int jj = 0; jj < 2; ++jj) {
    const int j = gg + 64*jj;
#pragma unroll
    for (int e4 = 0; e4 < 4; ++e4) {
      const float rr = sigmoidf_(sacc[jj][e4]);
      const float zz = sigmoidf_(sacc[2 + jj][e4]);
      const float hn = hacc[jj][e4];
      const float nn = tanhf(sacc[4 + jj][e4] + (rr - 1.0f) * hn);  // in_+hn + (r-1)hn = in_+r*hn
      const float h  = HT[j][ecol + e4];
      s.NT[j][ecol + e4] = (1.0f - zz) * nn + zz * h;
    }
  }
  __syncthreads();

  // ---- gate GEMM: sigmoid([h | nu] @ gate_w^T + b) ----
  float gacc[2][4] = {{0,0,0,0},{0,0,0,0}};
#pragma unroll 4
  for (int kk = 0; kk < 128; ++kk) {
    const float4 x = *(const float4*)&HT[kk][ecol];
    const float w0 = GWT[kk*128 + gg], w1 = GWT[kk*128 + gg + 64];
    gacc[0][0] += w0*x.x; gacc[0][1] += w0*x.y; gacc[0][2] += w0*x.z; gacc[0][3] += w0*x.w;
    gacc[1][0] += w1*x.x; gacc[1][1] += w1*x.y; gacc[1][2] += w1*x.z; gacc[1][3] += w1*x.w;
  }
#pragma unroll 4
  for (int kk = 0; kk < 128; ++kk) {
    const float4 x = *(const float4*)&s.NT[kk][ecol];
    const float w0 = GWT[(128 + kk)*128 + gg], w1 = GWT[(128 + kk)*128 + gg + 64];
    gacc[0][0] += w0*x.x; gacc[0][1] += w0*x.y; gacc[0][2] += w0*x.z; gacc[0][3] += w0*x.w;
    gacc[1][0] += w1*x.x; gacc[1][1] += w1*x.y; gacc[1][2] += w1*x.z; gacc[1][3] += w1*x.w;
  }
  const float gb0 = gate_b[gg], gb1 = gate_b[gg + 64];
#pragma unroll
  for (int jj = 0; jj < 2; ++jj) {
    const int j = gg + 64*jj;
#pragma unroll
    for (int e4 = 0; e4 < 4; ++e4) {
      const float g  = sigmoidf_(gacc[jj][e4] + (jj ? gb1 : gb0));
      const float nv = s.NT[j][ecol + e4];
      const float h  = HT[j][ecol + e4];
      outp[(size_t)(ecol + e4)*CE + j] = g * nv + (1.0f - g) * h;
    }
  }
  // no trailing sync: next phase's pre-elementwise sync guards NT reuse
}

extern "C" __global__ void prep_weights(
    const float* __restrict__ u_wih, const float* __restrict__ u_whh,
    const float* __restrict__ i_wih, const float* __restrict__ i_whh,
    const float* __restrict__ gate_w, const float* __restrict__ pred_w,
    float* __restrict__ ws)
{
  float* WUT = ws + WUT_OFF;
  float* WIT = ws + WIT_OFF;
  float* GWT = ws + GWT_OFF;
  float* PWT = ws + PWT_OFF;
  const int stride = gridDim.x * blockDim.x;
  const int idx = blockIdx.x * blockDim.x + threadIdx.x;
  for (int i = idx; i < 556*384; i += stride) {
    const int k = i / 384, g = i - k*384;
    WUT[i] = (k < 428) ? u_wih[(size_t)g*428 + k] : u_whh[(size_t)g*128 + (k - 428)];
    WIT[i] = (k < 428) ? i_wih[(size_t)g*428 + k] : i_whh[(size_t)g*128 + (k - 428)];
  }
  for (int i = idx; i < 256*128; i += stride) {
    const int k = i / 128, j = i - k*128;
    GWT[i] = gate_w[(size_t)j*256 + k];
  }
  for (int i = idx; i < 128*128; i += stride) {
    const int k = i / 128, j = i - k*128;
    PWT[i] = pred_w[(size_t)j*128 + k];
  }
}

extern "C" __global__ void __launch_bounds__(512)
jodie_main(const int* __restrict__ user_ids, const int* __restrict__ item_ids,
           const float* __restrict__ timestamps, const float* __restrict__ features,
           const int* __restrict__ query_time, const float* __restrict__ memv,
           const float* __restrict__ last_time, const float* __restrict__ time_w,
           const float* __restrict__ u_bih, const float* __restrict__ u_bhh,
           const float* __restrict__ i_bih, const float* __restrict__ i_bhh,
           const float* __restrict__ gate_b, const float* __restrict__ pred_b,
           const float* __restrict__ ws, float* __restrict__ d_out)
{
  __shared__ LdsBufs s;
  const int t  = threadIdx.x;
  const int e0 = blockIdx.x * 32;

  // ---- phase 0: gather + time projection into transposed LDS tiles ----
  {
    const int k  = t & 127;
    const int eb = t >> 7;                 // 0..3, 2 events' rows per iter pair
    const float qt  = (float)query_time[0];
    const float twk = time_w[k];
    for (int er = 0; er < 8; ++er) {
      const int e   = eb*8 + er;
      const int ge  = e0 + e;
      const int u   = user_ids[ge];
      const int itn = item_ids[ge] + CNU;
      const float ts = timestamps[ge];
      const float lu = last_time[u];
      const float li = last_time[itn];
      const float du = ts - lu, di = ts - li, dq = qt - lu;
      const float ou = memv[(size_t)u  *CE + k];
      const float oi = memv[(size_t)itn*CE + k];
      s.XC[k][e]       = ou * (1.0f + du*twk);   // pu
      s.XC[128 + k][e] = oi * (1.0f + di*twk);   // pi
      s.XC[428 + k][e] = ou;                     // ou (GRU h / gate input)
      s.OIT[k][e]      = oi;                     // oi
      s.NT[k][e]       = ou * (1.0f + dq*twk);   // qu (pred input)
    }
    for (int i = t; i < 32*CF; i += 512) {
      const int e = i / CF, f = i - e*CF;
      s.XC[256 + f][e] = features[(size_t)(e0 + e)*CF + f];
    }
  }
  __syncthreads();

  const int gg   = t & 63;
  const int eg   = t >> 6;      // 0..7 -> 4 events each
  const int ecol = eg * 4;
  const float* WUT = ws + WUT_OFF;
  const float* WIT = ws + WIT_OFF;
  const float* GWT = ws + GWT_OFF;
  const float* PWT = ws + PWT_OFF;

  // ---- pred: query_user @ pred_w^T + pred_b (reads NT=qu) ----
  {
    float pacc[2][4] = {{0,0,0,0},{0,0,0,0}};
#pragma unroll 4
    for (int kk = 0; kk < 128; ++kk) {
      const float4 x = *(const float4*)&s.NT[kk][ecol];
      const float w0 = PWT[kk*128 + gg], w1 = PWT[kk*128 + gg + 64];
      pacc[0][0] += w0*x.x; pacc[0][1] += w0*x.y; pacc[0][2] += w0*x.z; pacc[0][3] += w0*x.w;
      pacc[1][0] += w1*x.x; pacc[1][1] += w1*x.y; pacc[1][2] += w1*x.z; pacc[1][3] += w1*x.w;
    }
    const float pb0 = pred_b[gg], pb1 = pred_b[gg + 64];
#pragma unroll
    for (int e4 = 0; e4 < 4; ++e4) {
      const size_t ge = (size_t)(e0 + ecol + e4);
      d_out[ge*CE + gg]      = pacc[0][e4] + pb0;
      d_out[ge*CE + gg + 64] = pacc[1][e4] + pb1;
    }
  }

  // ---- user GRU (h = ou, x = [pu|pi|feat]) ----
  gru_phase<false>(s, WUT, u_bih, u_bhh, GWT, gate_b,
                   (const float(*)[LDSW])(s.XC + 428),
                   d_out + (size_t)CB*CE + (size_t)e0*CE, eg, gg);

  // ---- item GRU (h = oi, x = [pi|pu|feat] via row remap) ----
  gru_phase<true>(s, WIT, i_bih, i_bhh, GWT, gate_b,
                  (const float(*)[LDSW])s.OIT,
                  d_out + (size_t)2*CB*CE + (size_t)e0*CE, eg, gg);
}

extern "C" void kernel_launch(void* const* d_in, const int* in_sizes, int n_in,
                              void* d_out, int out_size, void* d_ws, size_t ws_size,
                              hipStream_t stream) {
  const int*   user_ids   = (const int*)d_in[0];
  const int*   item_ids   = (const int*)d_in[1];
  const float* timestamps = (const float*)d_in[2];
  const float* features   = (const float*)d_in[3];
  const int*   query_time = (const int*)d_in[4];
  const float* memv       = (const float*)d_in[5];
  const float* last_time  = (const float*)d_in[6];
  const float* time_w     = (const float*)d_in[7];
  const float* u_wih = (const float*)d_in[8];
  const float* u_whh = (const float*)d_in[9];
  const float* u_bih = (const float*)d_in[10];
  const float* u_bhh = (const float*)d_in[11];
  const float* i_wih = (const float*)d_in[12];
  const float* i_whh = (const float*)d_in[13];
  const float* i_bih = (const float*)d_in[14];
  const float* i_bhh = (const float*)d_in[15];
  const float* gate_w = (const float*)d_in[16];
  const float* gate_b = (const float*)d_in[17];
  const float* pred_w = (const float*)d_in[18];
  const float* pred_b = (const float*)d_in[19];
  float* ws  = (float*)d_ws;
  float* out = (float*)d_out;

  prep_weights<<<dim3(512), dim3(256), 0, stream>>>(u_wih, u_whh, i_wih, i_whh,
                                                    gate_w, pred_w, ws);
  jodie_main<<<dim3(CB/32), dim3(512), 0, stream>>>(user_ids, item_ids, timestamps,
                                                    features, query_time, memv,
                                                    last_time, time_w,
                                                    u_bih, u_bhh, i_bih, i_bhh,
                                                    gate_b, pred_b, ws, out);
}

// Round 2
// 222.158 us; speedup vs baseline: 6.0002x; 6.0002x over previous
//
#include <hip/hip_runtime.h>
#include <cstdint>
#include <cstddef>

// Problem constants
#define CNU 500000      // item id offset
#define CB  65536       // batch
#define CE  128         // embedding dim
#define CF  172         // feature dim
#define EV  32          // events per block

typedef unsigned short ushort_t;
typedef __attribute__((ext_vector_type(8))) short b8;    // 8 x bf16 (4 VGPRs)
typedef __attribute__((ext_vector_type(4))) float f4;    // MFMA accumulator

#define MFMA16(a,b,c) __builtin_amdgcn_mfma_f32_16x16x32_bf16((a),(b),(c),0,0,0)

// ---- packed weight layout in ws (ushort elements) ----
// B-fragment order: frag(nt,kt) = 64 lanes * 8 bf16; lane l holds
// B[k = kt*32 + (l>>4)*8 + j][n = nt*16 + (l&15)]  (B = W^T, i.e. B[k][n]=W[n][k])
#define FRAG 512
#define U_KT 18                   // 14 k-tiles of wih (K padded to 448) + 4 of whh
#define U_NT 24                   // 384 gate cols
#define U_SZ (U_NT*U_KT*FRAG)     // 221184
#define PU_OFF 0
#define PI_OFF U_SZ
#define PG_OFF (2*U_SZ)           // gate_w: 8 nt x 8 kt
#define G_SZ (8*8*FRAG)
#define PP_OFF (PG_OFF + G_SZ)    // pred_w: 8 nt x 4 kt
#define P_SZ (8*4*FRAG)

__device__ __forceinline__ ushort_t f2bf(float f) {
  unsigned u = __float_as_uint(f);
  return (ushort_t)((u + 0x7FFFu + ((u >> 16) & 1u)) >> 16);   // RNE
}
__device__ __forceinline__ float bf2f(ushort_t h) {
  return __uint_as_float(((unsigned)h) << 16);
}
__device__ __forceinline__ float sigmoid_(float x) { return 1.0f/(1.0f+__expf(-x)); }
__device__ __forceinline__ float tanh_(float x) { float e=__expf(2.0f*x); return 1.0f-2.0f/(e+1.0f); }

// ---- LDS tiles: bf16, row-major [event][k], row stride padded (+8) so that
// stride mod 128B == 16B -> A-fragment ds_read_b128 lands ~2-way (free). ----
struct __align__(16) SLds {
  ushort_t X  [EV][456];   // 0-127 pu | 128-255 pi | 256-427 feat | 428-447 zeros | pad
  ushort_t OUH[EV][264];   // 0-127 ou | 128-255 h'u | pad
  ushort_t OIH[EV][264];   // 0-127 oi | 128-255 h'i | pad
  ushort_t QU [EV][136];   // 0-127 qu | pad
};                         // total 71,680 B -> 2 blocks/CU

// One GRU: S = x@wih^T + h@whh^T (fused per-gate accs, gh_n kept separate),
// elementwise, h' -> H[.,128..255].
// Wave wv owns gate cols nt = {wv (r), wv+8 (z), wv+16 (n)}.
template<bool SWAP>
__device__ __forceinline__ void gru_run(SLds& s, const ushort_t* __restrict__ W,
    const float* __restrict__ bih, const float* __restrict__ bhh,
    ushort_t (*H)[264], int wv, int l)
{
  const int lrow = l & 15;
  const int lk   = (l >> 4) * 8;
  const int col  = wv*16 + lrow;

  const float br = bih[col]     + bhh[col];
  const float bz = bih[col+128] + bhh[col+128];
  const float bn = bih[col+256];
  const float bh = bhh[col+256];
  f4 ar[2], az[2], agin[2], aghn[2];
#pragma unroll
  for (int m = 0; m < 2; ++m) {
    ar[m]   = (f4){br,br,br,br};
    az[m]   = (f4){bz,bz,bz,bz};
    agin[m] = (f4){bn,bn,bn,bn};
    aghn[m] = (f4){bh,bh,bh,bh};
  }

  const ushort_t* Wr = W + ((size_t)(wv   )*U_KT)*FRAG + l*8;
  const ushort_t* Wz = W + ((size_t)(wv+ 8)*U_KT)*FRAG + l*8;
  const ushort_t* Wn = W + ((size_t)(wv+16)*U_KT)*FRAG + l*8;

  // ---- gi: X @ wih^T over K=448 (item remaps k-tiles: [pi|pu|feat]) ----
#pragma unroll
  for (int kt = 0; kt < 14; ++kt) {
    const int cb = SWAP ? ((kt < 4) ? 128 + 32*kt : ((kt < 8) ? 32*(kt-4) : 32*kt))
                        : 32*kt;
    b8 a0 = *(const b8*)&s.X[lrow][cb + lk];
    b8 a1 = *(const b8*)&s.X[16 + lrow][cb + lk];
    b8 fr = *(const b8*)(Wr + (size_t)kt*FRAG);
    b8 fz = *(const b8*)(Wz + (size_t)kt*FRAG);
    b8 fn = *(const b8*)(Wn + (size_t)kt*FRAG);
    ar[0]   = MFMA16(a0, fr, ar[0]);   ar[1]   = MFMA16(a1, fr, ar[1]);
    az[0]   = MFMA16(a0, fz, az[0]);   az[1]   = MFMA16(a1, fz, az[1]);
    agin[0] = MFMA16(a0, fn, agin[0]); agin[1] = MFMA16(a1, fn, agin[1]);
  }
  // ---- gh: h @ whh^T over K=128 (r,z continue; n separate) ----
#pragma unroll
  for (int kt = 0; kt < 4; ++kt) {
    b8 h0 = *(const b8*)&H[lrow][32*kt + lk];
    b8 h1 = *(const b8*)&H[16 + lrow][32*kt + lk];
    b8 fr = *(const b8*)(Wr + (size_t)(14+kt)*FRAG);
    b8 fz = *(const b8*)(Wz + (size_t)(14+kt)*FRAG);
    b8 fn = *(const b8*)(Wn + (size_t)(14+kt)*FRAG);
    ar[0]   = MFMA16(h0, fr, ar[0]);   ar[1]   = MFMA16(h1, fr, ar[1]);
    az[0]   = MFMA16(h0, fz, az[0]);   az[1]   = MFMA16(h1, fz, az[1]);
    aghn[0] = MFMA16(h0, fn, aghn[0]); aghn[1] = MFMA16(h1, fn, aghn[1]);
  }

  // ---- elementwise: D[row=(l>>4)*4+r4][col=l&15] per m-tile ----
#pragma unroll
  for (int m = 0; m < 2; ++m) {
#pragma unroll
    for (int r4 = 0; r4 < 4; ++r4) {
      const int row = m*16 + (l >> 4)*4 + r4;
      const float rr = sigmoid_(ar[m][r4]);
      const float zz = sigmoid_(az[m][r4]);
      const float nn = tanh_(agin[m][r4] + rr*aghn[m][r4]);
      const float h  = bf2f(H[row][col]);
      H[row][128 + col] = f2bf((1.0f - zz)*nn + zz*h);
    }
  }
}

extern "C" __global__ void prep_weights(
    const float* __restrict__ u_wih, const float* __restrict__ u_whh,
    const float* __restrict__ i_wih, const float* __restrict__ i_whh,
    const float* __restrict__ gate_w, const float* __restrict__ pred_w,
    ushort_t* __restrict__ ws)
{
  const int stride = gridDim.x * blockDim.x;
  const int tid = blockIdx.x * blockDim.x + threadIdx.x;
  for (int i = tid; i < U_SZ; i += stride) {
    const int nt = i / (U_KT*FRAG);
    const int r1 = i - nt*(U_KT*FRAG);
    const int kt = r1 / FRAG;
    const int e  = r1 - kt*FRAG;
    const int l  = e >> 3, j = e & 7;
    const int n  = nt*16 + (l & 15);
    const int k  = (l >> 4)*8 + j;
    float vu, vi;
    if (kt < 14) {
      const int kk = kt*32 + k;
      vu = (kk < 428) ? u_wih[(size_t)n*428 + kk] : 0.0f;
      vi = (kk < 428) ? i_wih[(size_t)n*428 + kk] : 0.0f;
    } else {
      const int kk = (kt - 14)*32 + k;
      vu = u_whh[(size_t)n*128 + kk];
      vi = i_whh[(size_t)n*128 + kk];
    }
    ws[PU_OFF + i] = f2bf(vu);
    ws[PI_OFF + i] = f2bf(vi);
  }
  for (int i = tid; i < G_SZ; i += stride) {
    const int nt = i / (8*FRAG);
    const int r1 = i - nt*(8*FRAG);
    const int kt = r1 / FRAG;
    const int e  = r1 - kt*FRAG;
    const int l  = e >> 3, j = e & 7;
    const int n  = nt*16 + (l & 15);
    const int kk = kt*32 + (l >> 4)*8 + j;
    ws[PG_OFF + i] = f2bf(gate_w[(size_t)n*256 + kk]);
  }
  for (int i = tid; i < P_SZ; i += stride) {
    const int nt = i / (4*FRAG);
    const int r1 = i - nt*(4*FRAG);
    const int kt = r1 / FRAG;
    const int e  = r1 - kt*FRAG;
    const int l  = e >> 3, j = e & 7;
    const int n  = nt*16 + (l & 15);
    const int kk = kt*32 + (l >> 4)*8 + j;
    ws[PP_OFF + i] = f2bf(pred_w[(size_t)n*128 + kk]);
  }
}

extern "C" __global__ void __launch_bounds__(512, 4)
jodie_main(const int* __restrict__ user_ids, const int* __restrict__ item_ids,
           const float* __restrict__ timestamps, const float* __restrict__ features,
           const int* __restrict__ query_time, const float* __restrict__ memv,
           const float* __restrict__ last_time, const float* __restrict__ time_w,
           const float* __restrict__ u_bih, const float* __restrict__ u_bhh,
           const float* __restrict__ i_bih, const float* __restrict__ i_bhh,
           const float* __restrict__ gate_b, const float* __restrict__ pred_b,
           const ushort_t* __restrict__ ws, float* __restrict__ d_out)
{
  __shared__ SLds s;
  const int t  = threadIdx.x;
  const int e0 = blockIdx.x * EV;

  // ---- staging: 16 threads/event, 8 cols each ----
  {
    const int e  = t >> 4;
    const int c8 = (t & 15) * 8;
    const int ge = e0 + e;
    const int u   = user_ids[ge];
    const int itn = item_ids[ge] + CNU;
    const float ts = timestamps[ge];
    const float lu = last_time[u];
    const float li = last_time[itn];
    const float qt = (float)query_time[0];
    const float du = ts - lu, di = ts - li, dq = qt - lu;

    const float4 tw0 = *(const float4*)&time_w[c8];
    const float4 tw1 = *(const float4*)&time_w[c8 + 4];
    const float4 ou0 = *(const float4*)&memv[(size_t)u  *CE + c8];
    const float4 ou1 = *(const float4*)&memv[(size_t)u  *CE + c8 + 4];
    const float4 oi0 = *(const float4*)&memv[(size_t)itn*CE + c8];
    const float4 oi1 = *(const float4*)&memv[(size_t)itn*CE + c8 + 4];
    const float twv[8] = {tw0.x,tw0.y,tw0.z,tw0.w, tw1.x,tw1.y,tw1.z,tw1.w};
    const float ouv[8] = {ou0.x,ou0.y,ou0.z,ou0.w, ou1.x,ou1.y,ou1.z,ou1.w};
    const float oiv[8] = {oi0.x,oi0.y,oi0.z,oi0.w, oi1.x,oi1.y,oi1.z,oi1.w};

    union { ushort_t u[8]; b8 v; } xu, xi, hu, hi, qv;
#pragma unroll
    for (int j = 0; j < 8; ++j) {
      xu.u[j] = f2bf(ouv[j] * (1.0f + du*twv[j]));
      xi.u[j] = f2bf(oiv[j] * (1.0f + di*twv[j]));
      hu.u[j] = f2bf(ouv[j]);
      hi.u[j] = f2bf(oiv[j]);
      qv.u[j] = f2bf(ouv[j] * (1.0f + dq*twv[j]));
    }
    *(b8*)&s.X  [e][c8]       = xu.v;
    *(b8*)&s.X  [e][128 + c8] = xi.v;
    *(b8*)&s.OUH[e][c8]       = hu.v;
    *(b8*)&s.OIH[e][c8]       = hi.v;
    *(b8*)&s.QU [e][c8]       = qv.v;

    // features (ragged 11 cols per thread)
    const int f0 = (t & 15) * 11;
#pragma unroll
    for (int f = f0; f < f0 + 11; ++f)
      if (f < CF) s.X[e][256 + f] = f2bf(features[(size_t)ge*CF + f]);
    // zero-pad k = 428..447
    s.X[e][428 + (t & 15)] = 0;
    if ((t & 15) < 4) s.X[e][444 + (t & 15)] = 0;
  }
  __syncthreads();

  const int wv = t >> 6, l = t & 63;
  const int lrow = l & 15;
  const int lk   = (l >> 4) * 8;
  const int col  = wv*16 + lrow;

  // ---- user GRU then item GRU (h' lands in OUH/OIH cols 128-255) ----
  gru_run<false>(s, ws + PU_OFF, u_bih, u_bhh, s.OUH, wv, l);
  gru_run<true >(s, ws + PI_OFF, i_bih, i_bhh, s.OIH, wv, l);
  __syncthreads();   // h' from all waves visible before gate GEMM

  // ---- pred: qu @ pred_w^T + pred_b ----
  {
    const float bp = pred_b[col];
    f4 ap[2];
    ap[0] = (f4){bp,bp,bp,bp};
    ap[1] = ap[0];
    const ushort_t* WP = ws + PP_OFF + ((size_t)wv*4)*FRAG + l*8;
#pragma unroll
    for (int kt = 0; kt < 4; ++kt) {
      b8 a0 = *(const b8*)&s.QU[lrow][32*kt + lk];
      b8 a1 = *(const b8*)&s.QU[16 + lrow][32*kt + lk];
      b8 fp = *(const b8*)(WP + (size_t)kt*FRAG);
      ap[0] = MFMA16(a0, fp, ap[0]);
      ap[1] = MFMA16(a1, fp, ap[1]);
    }
#pragma unroll
    for (int m = 0; m < 2; ++m)
#pragma unroll
      for (int r4 = 0; r4 < 4; ++r4) {
        const int row = m*16 + (l >> 4)*4 + r4;
        d_out[(size_t)(e0 + row)*CE + col] = ap[m][r4];
      }
  }

  // ---- memory gates (shared gate_w fragments feed user AND item) ----
  {
    const float gb = gate_b[col];
    f4 agu[2], agi[2];
    agu[0] = (f4){gb,gb,gb,gb};
    agu[1] = agu[0]; agi[0] = agu[0]; agi[1] = agu[0];
    const ushort_t* WG = ws + PG_OFF + ((size_t)wv*8)*FRAG + l*8;
#pragma unroll
    for (int kt = 0; kt < 8; ++kt) {
      b8 fg  = *(const b8*)(WG + (size_t)kt*FRAG);
      b8 au0 = *(const b8*)&s.OUH[lrow][32*kt + lk];
      b8 au1 = *(const b8*)&s.OUH[16 + lrow][32*kt + lk];
      b8 ai0 = *(const b8*)&s.OIH[lrow][32*kt + lk];
      b8 ai1 = *(const b8*)&s.OIH[16 + lrow][32*kt + lk];
      agu[0] = MFMA16(au0, fg, agu[0]);
      agu[1] = MFMA16(au1, fg, agu[1]);
      agi[0] = MFMA16(ai0, fg, agi[0]);
      agi[1] = MFMA16(ai1, fg, agi[1]);
    }
    float* __restrict__ outu = d_out + (size_t)CB*CE;
    float* __restrict__ outi = d_out + (size_t)2*CB*CE;
#pragma unroll
    for (int m = 0; m < 2; ++m)
#pragma unroll
      for (int r4 = 0; r4 < 4; ++r4) {
        const int row = m*16 + (l >> 4)*4 + r4;
        const float gu = sigmoid_(agu[m][r4]);
        const float gi = sigmoid_(agi[m][r4]);
        const float hu  = bf2f(s.OUH[row][col]);
        const float hpu = bf2f(s.OUH[row][128 + col]);
        const float hi  = bf2f(s.OIH[row][col]);
        const float hpi = bf2f(s.OIH[row][128 + col]);
        outu[(size_t)(e0 + row)*CE + col] = gu*hpu + (1.0f - gu)*hu;
        outi[(size_t)(e0 + row)*CE + col] = gi*hpi + (1.0f - gi)*hi;
      }
  }
}

extern "C" void kernel_launch(void* const* d_in, const int* in_sizes, int n_in,
                              void* d_out, int out_size, void* d_ws, size_t ws_size,
                              hipStream_t stream) {
  const int*   user_ids   = (const int*)d_in[0];
  const int*   item_ids   = (const int*)d_in[1];
  const float* timestamps = (const float*)d_in[2];
  const float* features   = (const float*)d_in[3];
  const int*   query_time = (const int*)d_in[4];
  const float* memv       = (const float*)d_in[5];
  const float* last_time  = (const float*)d_in[6];
  const float* time_w     = (const float*)d_in[7];
  const float* u_wih = (const float*)d_in[8];
  const float* u_whh = (const float*)d_in[9];
  const float* u_bih = (const float*)d_in[10];
  const float* u_bhh = (const float*)d_in[11];
  const float* i_wih = (const float*)d_in[12];
  const float* i_whh = (const float*)d_in[13];
  const float* i_bih = (const float*)d_in[14];
  const float* i_bhh = (const float*)d_in[15];
  const float* gate_w = (const float*)d_in[16];
  const float* gate_b = (const float*)d_in[17];
  const float* pred_w = (const float*)d_in[18];
  const float* pred_b = (const float*)d_in[19];
  ushort_t* ws = (ushort_t*)d_ws;
  float* out = (float*)d_out;

  prep_weights<<<dim3(256), dim3(256), 0, stream>>>(u_wih, u_whh, i_wih, i_whh,
                                                    gate_w, pred_w, ws);
  jodie_main<<<dim3(CB/EV), dim3(512), 0, stream>>>(user_ids, item_ids, timestamps,
                                                    features, query_time, memv,
                                                    last_time, time_w,
                                                    u_bih, u_bhh, i_bih, i_bhh,
                                                    gate_b, pred_b, ws, out);
}

// Round 3
// 146.470 us; speedup vs baseline: 9.1008x; 1.5167x over previous
//
#include <hip/hip_runtime.h>
#include <cstdint>
#include <cstddef>

// Problem constants
#define CNU 500000      // item id offset
#define CB  65536       // batch
#define CE  128         // embedding dim
#define CF  172         // feature dim
#define EV  32          // events per block

typedef unsigned short ushort_t;
typedef __attribute__((ext_vector_type(8))) short b8;    // 8 x bf16
typedef __attribute__((ext_vector_type(4))) short b4;    // 4 x bf16
typedef __attribute__((ext_vector_type(4))) float f4;    // MFMA accumulator

#define MFMA16(a,b,c) __builtin_amdgcn_mfma_f32_16x16x32_bf16((a),(b),(c),0,0,0)

// ---- packed weight layout in ws (ushort elements), B-fragment order:
// frag(nt,kt): lane l holds B[k=kt*32+(l>>4)*8+j][n=nt*16+(l&15)], j=0..7
#define FRAG 512
#define U_KT 18                   // 14 k-tiles wih (K pad 448) + 4 whh
#define U_NT 24
#define U_SZ (U_NT*U_KT*FRAG)
#define PU_OFF 0
#define PI_OFF U_SZ
#define PG_OFF (2*U_SZ)
#define G_SZ (8*8*FRAG)
#define PP_OFF (PG_OFF + G_SZ)
#define P_SZ (8*4*FRAG)

// XOR-swizzle: flip 16B-granule index (bits 3-5 of ushort col) by row&7.
// Applied on BOTH write and read sides of every LDS tile (T2 discipline).
#define SWZ(r, c) ((c) ^ (((r) & 7) << 3))
#define AFRAG(T, r, c) (*(const b8*)&(T)[(r)][SWZ((r), (c))])

__device__ __forceinline__ ushort_t f2bf(float f) {
  unsigned u = __float_as_uint(f);
  return (ushort_t)((u + 0x7FFFu + ((u >> 16) & 1u)) >> 16);   // RNE
}
__device__ __forceinline__ float bf2f(ushort_t h) {
  return __uint_as_float(((unsigned)h) << 16);
}
__device__ __forceinline__ float sigmoid_(float x) { return 1.0f/(1.0f+__expf(-x)); }
__device__ __forceinline__ float tanh_(float x) { float e=__expf(2.0f*x); return 1.0f-2.0f/(e+1.0f); }

// ---- LDS: per-quantity [EV][128] bf16 sub-tiles, 256B rows, XOR-swizzled ----
struct __align__(16) SLds {
  ushort_t PU[EV][128];   // proj_user
  ushort_t PI[EV][128];   // proj_item
  ushort_t FE[EV][192];   // features (cols 172-191 zero)
  ushort_t OU[EV][128];   // old_user (h_u)
  ushort_t OI[EV][128];   // old_item (h_i)
  ushort_t HU[EV][128];   // h'_u
  ushort_t HI[EV][128];   // h'_i
  ushort_t QU[EV][128];   // query_user
};                        // 69,632 B -> 2 blocks/CU

extern "C" __global__ void prep_weights(
    const float* __restrict__ u_wih, const float* __restrict__ u_whh,
    const float* __restrict__ i_wih, const float* __restrict__ i_whh,
    const float* __restrict__ gate_w, const float* __restrict__ pred_w,
    ushort_t* __restrict__ ws)
{
  const int stride = gridDim.x * blockDim.x;
  const int tid = blockIdx.x * blockDim.x + threadIdx.x;
  for (int i = tid; i < U_SZ; i += stride) {
    const int nt = i / (U_KT*FRAG);
    const int r1 = i - nt*(U_KT*FRAG);
    const int kt = r1 / FRAG;
    const int e  = r1 - kt*FRAG;
    const int l  = e >> 3, j = e & 7;
    const int n  = nt*16 + (l & 15);
    const int k  = (l >> 4)*8 + j;
    float vu, vi;
    if (kt < 14) {
      const int kk = kt*32 + k;
      vu = (kk < 428) ? u_wih[(size_t)n*428 + kk] : 0.0f;
      vi = (kk < 428) ? i_wih[(size_t)n*428 + kk] : 0.0f;
    } else {
      const int kk = (kt - 14)*32 + k;
      vu = u_whh[(size_t)n*128 + kk];
      vi = i_whh[(size_t)n*128 + kk];
    }
    ws[PU_OFF + i] = f2bf(vu);
    ws[PI_OFF + i] = f2bf(vi);
  }
  for (int i = tid; i < G_SZ; i += stride) {
    const int nt = i / (8*FRAG);
    const int r1 = i - nt*(8*FRAG);
    const int kt = r1 / FRAG;
    const int e  = r1 - kt*FRAG;
    const int l  = e >> 3, j = e & 7;
    const int n  = nt*16 + (l & 15);
    const int kk = kt*32 + (l >> 4)*8 + j;
    ws[PG_OFF + i] = f2bf(gate_w[(size_t)n*256 + kk]);
  }
  for (int i = tid; i < P_SZ; i += stride) {
    const int nt = i / (4*FRAG);
    const int r1 = i - nt*(4*FRAG);
    const int kt = r1 / FRAG;
    const int e  = r1 - kt*FRAG;
    const int l  = e >> 3, j = e & 7;
    const int n  = nt*16 + (l & 15);
    const int kk = kt*32 + (l >> 4)*8 + j;
    ws[PP_OFF + i] = f2bf(pred_w[(size_t)n*128 + kk]);
  }
}

extern "C" __global__ void __launch_bounds__(512, 4)
jodie_main(const int* __restrict__ user_ids, const int* __restrict__ item_ids,
           const float* __restrict__ timestamps, const float* __restrict__ features,
           const int* __restrict__ query_time, const float* __restrict__ memv,
           const float* __restrict__ last_time, const float* __restrict__ time_w,
           const float* __restrict__ u_bih, const float* __restrict__ u_bhh,
           const float* __restrict__ i_bih, const float* __restrict__ i_bhh,
           const float* __restrict__ gate_b, const float* __restrict__ pred_b,
           const ushort_t* __restrict__ ws, float* __restrict__ d_out)
{
  __shared__ SLds s;
  const int t  = threadIdx.x;
  const int e0 = blockIdx.x * EV;

  // ---- stage: 16 threads/event, 8 cols each (swizzled b8 writes) ----
  {
    const int e  = t >> 4;
    const int c8 = (t & 15) * 8;
    const int ge = e0 + e;
    const int u   = user_ids[ge];
    const int itn = item_ids[ge] + CNU;
    const float ts = timestamps[ge];
    const float lu = last_time[u];
    const float li = last_time[itn];
    const float qt = (float)query_time[0];
    const float du = ts - lu, di = ts - li, dq = qt - lu;

    const float4 tw0 = *(const float4*)&time_w[c8];
    const float4 tw1 = *(const float4*)&time_w[c8 + 4];
    const float4 ou0 = *(const float4*)&memv[(size_t)u  *CE + c8];
    const float4 ou1 = *(const float4*)&memv[(size_t)u  *CE + c8 + 4];
    const float4 oi0 = *(const float4*)&memv[(size_t)itn*CE + c8];
    const float4 oi1 = *(const float4*)&memv[(size_t)itn*CE + c8 + 4];
    const float twv[8] = {tw0.x,tw0.y,tw0.z,tw0.w, tw1.x,tw1.y,tw1.z,tw1.w};
    const float ouv[8] = {ou0.x,ou0.y,ou0.z,ou0.w, ou1.x,ou1.y,ou1.z,ou1.w};
    const float oiv[8] = {oi0.x,oi0.y,oi0.z,oi0.w, oi1.x,oi1.y,oi1.z,oi1.w};

    union { ushort_t u[8]; b8 v; } xu, xi, hu, hi, qv;
#pragma unroll
    for (int j = 0; j < 8; ++j) {
      xu.u[j] = f2bf(ouv[j] * (1.0f + du*twv[j]));
      xi.u[j] = f2bf(oiv[j] * (1.0f + di*twv[j]));
      hu.u[j] = f2bf(ouv[j]);
      hi.u[j] = f2bf(oiv[j]);
      qv.u[j] = f2bf(ouv[j] * (1.0f + dq*twv[j]));
    }
    *(b8*)&s.PU[e][SWZ(e, c8)] = xu.v;
    *(b8*)&s.PI[e][SWZ(e, c8)] = xi.v;
    *(b8*)&s.OU[e][SWZ(e, c8)] = hu.v;
    *(b8*)&s.OI[e][SWZ(e, c8)] = hi.v;
    *(b8*)&s.QU[e][SWZ(e, c8)] = qv.v;
  }
  // ---- features: exact float4 tiling (172 = 43*4; 688B rows are 16B-aligned) ----
  for (int i = t; i < EV*43; i += 512) {
    const int e = i / 43, q = i - e*43;
    const float4 fv = *(const float4*)&features[(size_t)(e0 + e)*CF + q*4];
    union { ushort_t u[4]; b4 v; } fb;
    fb.u[0] = f2bf(fv.x); fb.u[1] = f2bf(fv.y);
    fb.u[2] = f2bf(fv.z); fb.u[3] = f2bf(fv.w);
    *(b4*)&s.FE[e][SWZ(e, q*4)] = fb.v;
  }
  // zero-pad feature cols 172..191
  for (int i = t; i < EV*20; i += 512) {
    const int e = i / 20, c = 172 + (i - e*20);
    s.FE[e][SWZ(e, c)] = 0;
  }
  __syncthreads();

  const int wv   = t >> 6, l = t & 63;
  const int lrow = l & 15;
  const int lk   = (l >> 4) * 8;
  const int col  = wv*16 + lrow;

  // ---- biases ----
  const float bru = u_bih[col]     + u_bhh[col];
  const float bzu = u_bih[col+128] + u_bhh[col+128];
  const float bnu = u_bih[col+256];
  const float bhu = u_bhh[col+256];
  const float bri = i_bih[col]     + i_bhh[col];
  const float bzi = i_bih[col+128] + i_bhh[col+128];
  const float bni = i_bih[col+256];
  const float bhi = i_bhh[col+256];

  f4 aru[2], azu[2], anu[2], ari[2], azi[2], ani[2];
#pragma unroll
  for (int m = 0; m < 2; ++m) {
    aru[m] = (f4){bru,bru,bru,bru};  azu[m] = (f4){bzu,bzu,bzu,bzu};
    anu[m] = (f4){bnu,bnu,bnu,bnu};  ari[m] = (f4){bri,bri,bri,bri};
    azi[m] = (f4){bzi,bzi,bzi,bzi};  ani[m] = (f4){bni,bni,bni,bni};
  }

  const ushort_t* Wru = ws + PU_OFF + (size_t)(wv     )*U_KT*FRAG + l*8;
  const ushort_t* Wzu = ws + PU_OFF + (size_t)(wv +  8)*U_KT*FRAG + l*8;
  const ushort_t* Wnu = ws + PU_OFF + (size_t)(wv + 16)*U_KT*FRAG + l*8;
  const ushort_t* Wri = ws + PI_OFF + (size_t)(wv     )*U_KT*FRAG + l*8;
  const ushort_t* Wzi = ws + PI_OFF + (size_t)(wv +  8)*U_KT*FRAG + l*8;
  const ushort_t* Wni = ws + PI_OFF + (size_t)(wv + 16)*U_KT*FRAG + l*8;

  // ---- FUSED gi: one A-fragment pair feeds both GRUs (item = kt permute) ----
#pragma unroll
  for (int pf = 0; pf < 14; ++pf) {
    const int kti = (pf < 4) ? pf + 4 : (pf < 8) ? pf - 4 : pf;   // item weight kt
    b8 a0, a1;
    if (pf < 4)       { a0 = AFRAG(s.PU, lrow, 32*pf + lk);     a1 = AFRAG(s.PU, 16+lrow, 32*pf + lk); }
    else if (pf < 8)  { a0 = AFRAG(s.PI, lrow, 32*(pf-4) + lk); a1 = AFRAG(s.PI, 16+lrow, 32*(pf-4) + lk); }
    else              { a0 = AFRAG(s.FE, lrow, 32*(pf-8) + lk); a1 = AFRAG(s.FE, 16+lrow, 32*(pf-8) + lk); }
    b8 fru = *(const b8*)(Wru + (size_t)pf*FRAG);
    b8 fzu = *(const b8*)(Wzu + (size_t)pf*FRAG);
    b8 fnu = *(const b8*)(Wnu + (size_t)pf*FRAG);
    b8 fri = *(const b8*)(Wri + (size_t)kti*FRAG);
    b8 fzi = *(const b8*)(Wzi + (size_t)kti*FRAG);
    b8 fni = *(const b8*)(Wni + (size_t)kti*FRAG);
    aru[0] = MFMA16(a0, fru, aru[0]);  aru[1] = MFMA16(a1, fru, aru[1]);
    azu[0] = MFMA16(a0, fzu, azu[0]);  azu[1] = MFMA16(a1, fzu, azu[1]);
    anu[0] = MFMA16(a0, fnu, anu[0]);  anu[1] = MFMA16(a1, fnu, anu[1]);
    ari[0] = MFMA16(a0, fri, ari[0]);  ari[1] = MFMA16(a1, fri, ari[1]);
    azi[0] = MFMA16(a0, fzi, azi[0]);  azi[1] = MFMA16(a1, fzi, azi[1]);
    ani[0] = MFMA16(a0, fni, ani[0]);  ani[1] = MFMA16(a1, fni, ani[1]);
  }

  // ---- user gh (K=128) + elementwise -> HU ----
  {
    f4 ah[2];
    ah[0] = (f4){bhu,bhu,bhu,bhu}; ah[1] = ah[0];
#pragma unroll
    for (int kt = 0; kt < 4; ++kt) {
      b8 h0 = AFRAG(s.OU, lrow, 32*kt + lk);
      b8 h1 = AFRAG(s.OU, 16+lrow, 32*kt + lk);
      b8 fr = *(const b8*)(Wru + (size_t)(14+kt)*FRAG);
      b8 fz = *(const b8*)(Wzu + (size_t)(14+kt)*FRAG);
      b8 fn = *(const b8*)(Wnu + (size_t)(14+kt)*FRAG);
      aru[0] = MFMA16(h0, fr, aru[0]);  aru[1] = MFMA16(h1, fr, aru[1]);
      azu[0] = MFMA16(h0, fz, azu[0]);  azu[1] = MFMA16(h1, fz, azu[1]);
      ah[0]  = MFMA16(h0, fn, ah[0]);   ah[1]  = MFMA16(h1, fn, ah[1]);
    }
#pragma unroll
    for (int m = 0; m < 2; ++m)
#pragma unroll
      for (int r4 = 0; r4 < 4; ++r4) {
        const int row = m*16 + (l >> 4)*4 + r4;
        const float rr = sigmoid_(aru[m][r4]);
        const float zz = sigmoid_(azu[m][r4]);
        const float nn = tanh_(anu[m][r4] + rr*ah[m][r4]);
        const float h  = bf2f(s.OU[row][SWZ(row, col)]);
        s.HU[row][SWZ(row, col)] = f2bf((1.0f - zz)*nn + zz*h);
      }
  }

  // ---- item gh + elementwise -> HI ----
  {
    f4 ah[2];
    ah[0] = (f4){bhi,bhi,bhi,bhi}; ah[1] = ah[0];
#pragma unroll
    for (int kt = 0; kt < 4; ++kt) {
      b8 h0 = AFRAG(s.OI, lrow, 32*kt + lk);
      b8 h1 = AFRAG(s.OI, 16+lrow, 32*kt + lk);
      b8 fr = *(const b8*)(Wri + (size_t)(14+kt)*FRAG);
      b8 fz = *(const b8*)(Wzi + (size_t)(14+kt)*FRAG);
      b8 fn = *(const b8*)(Wni + (size_t)(14+kt)*FRAG);
      ari[0] = MFMA16(h0, fr, ari[0]);  ari[1] = MFMA16(h1, fr, ari[1]);
      azi[0] = MFMA16(h0, fz, azi[0]);  azi[1] = MFMA16(h1, fz, azi[1]);
      ah[0]  = MFMA16(h0, fn, ah[0]);   ah[1]  = MFMA16(h1, fn, ah[1]);
    }
#pragma unroll
    for (int m = 0; m < 2; ++m)
#pragma unroll
      for (int r4 = 0; r4 < 4; ++r4) {
        const int row = m*16 + (l >> 4)*4 + r4;
        const float rr = sigmoid_(ari[m][r4]);
        const float zz = sigmoid_(azi[m][r4]);
        const float nn = tanh_(ani[m][r4] + rr*ah[m][r4]);
        const float h  = bf2f(s.OI[row][SWZ(row, col)]);
        s.HI[row][SWZ(row, col)] = f2bf((1.0f - zz)*nn + zz*h);
      }
  }

  // ---- pred: qu @ pred_w^T + pred_b (independent; overlaps ew latency) ----
  {
    const float bp = pred_b[col];
    f4 ap[2];
    ap[0] = (f4){bp,bp,bp,bp}; ap[1] = ap[0];
    const ushort_t* WP = ws + PP_OFF + (size_t)wv*4*FRAG + l*8;
#pragma unroll
    for (int kt = 0; kt < 4; ++kt) {
      b8 a0 = AFRAG(s.QU, lrow, 32*kt + lk);
      b8 a1 = AFRAG(s.QU, 16+lrow, 32*kt + lk);
      b8 fp = *(const b8*)(WP + (size_t)kt*FRAG);
      ap[0] = MFMA16(a0, fp, ap[0]);
      ap[1] = MFMA16(a1, fp, ap[1]);
    }
#pragma unroll
    for (int m = 0; m < 2; ++m)
#pragma unroll
      for (int r4 = 0; r4 < 4; ++r4) {
        const int row = m*16 + (l >> 4)*4 + r4;
        d_out[(size_t)(e0 + row)*CE + col] = ap[m][r4];
      }
  }

  __syncthreads();   // HU/HI from all waves visible

  // ---- memory gates: shared gate_w fragments, user+item A streams ----
  {
    const float gb = gate_b[col];
    f4 agu[2], agi[2];
    agu[0] = (f4){gb,gb,gb,gb};
    agu[1] = agu[0]; agi[0] = agu[0]; agi[1] = agu[0];
    const ushort_t* WG = ws + PG_OFF + (size_t)wv*8*FRAG + l*8;
#pragma unroll
    for (int kt = 0; kt < 8; ++kt) {
      b8 fg = *(const b8*)(WG + (size_t)kt*FRAG);
      b8 au0, au1, ai0, ai1;
      if (kt < 4) {
        au0 = AFRAG(s.OU, lrow, 32*kt + lk);  au1 = AFRAG(s.OU, 16+lrow, 32*kt + lk);
        ai0 = AFRAG(s.OI, lrow, 32*kt + lk);  ai1 = AFRAG(s.OI, 16+lrow, 32*kt + lk);
      } else {
        au0 = AFRAG(s.HU, lrow, 32*(kt-4) + lk);  au1 = AFRAG(s.HU, 16+lrow, 32*(kt-4) + lk);
        ai0 = AFRAG(s.HI, lrow, 32*(kt-4) + lk);  ai1 = AFRAG(s.HI, 16+lrow, 32*(kt-4) + lk);
      }
      agu[0] = MFMA16(au0, fg, agu[0]);
      agu[1] = MFMA16(au1, fg, agu[1]);
      agi[0] = MFMA16(ai0, fg, agi[0]);
      agi[1] = MFMA16(ai1, fg, agi[1]);
    }
    float* __restrict__ outu = d_out + (size_t)CB*CE;
    float* __restrict__ outi = d_out + (size_t)2*CB*CE;
#pragma unroll
    for (int m = 0; m < 2; ++m)
#pragma unroll
      for (int r4 = 0; r4 < 4; ++r4) {
        const int row = m*16 + (l >> 4)*4 + r4;
        const float gu = sigmoid_(agu[m][r4]);
        const float gi = sigmoid_(agi[m][r4]);
        const float hu  = bf2f(s.OU[row][SWZ(row, col)]);
        const float hpu = bf2f(s.HU[row][SWZ(row, col)]);
        const float hi  = bf2f(s.OI[row][SWZ(row, col)]);
        const float hpi = bf2f(s.HI[row][SWZ(row, col)]);
        outu[(size_t)(e0 + row)*CE + col] = gu*hpu + (1.0f - gu)*hu;
        outi[(size_t)(e0 + row)*CE + col] = gi*hpi + (1.0f - gi)*hi;
      }
  }
}

extern "C" void kernel_launch(void* const* d_in, const int* in_sizes, int n_in,
                              void* d_out, int out_size, void* d_ws, size_t ws_size,
                              hipStream_t stream) {
  const int*   user_ids   = (const int*)d_in[0];
  const int*   item_ids   = (const int*)d_in[1];
  const float* timestamps = (const float*)d_in[2];
  const float* features   = (const float*)d_in[3];
  const int*   query_time = (const int*)d_in[4];
  const float* memv       = (const float*)d_in[5];
  const float* last_time  = (const float*)d_in[6];
  const float* time_w     = (const float*)d_in[7];
  const float* u_wih = (const float*)d_in[8];
  const float* u_whh = (const float*)d_in[9];
  const float* u_bih = (const float*)d_in[10];
  const float* u_bhh = (const float*)d_in[11];
  const float* i_wih = (const float*)d_in[12];
  const float* i_whh = (const float*)d_in[13];
  const float* i_bih = (const float*)d_in[14];
  const float* i_bhh = (const float*)d_in[15];
  const float* gate_w = (const float*)d_in[16];
  const float* gate_b = (const float*)d_in[17];
  const float* pred_w = (const float*)d_in[18];
  const float* pred_b = (const float*)d_in[19];
  ushort_t* ws = (ushort_t*)d_ws;
  float* out = (float*)d_out;

  prep_weights<<<dim3(256), dim3(256), 0, stream>>>(u_wih, u_whh, i_wih, i_whh,
                                                    gate_w, pred_w, ws);
  jodie_main<<<dim3(CB/EV), dim3(512), 0, stream>>>(user_ids, item_ids, timestamps,
                                                    features, query_time, memv,
                                                    last_time, time_w,
                                                    u_bih, u_bhh, i_bih, i_bhh,
                                                    gate_b, pred_b, ws, out);
}

// Round 4
// 140.115 us; speedup vs baseline: 9.5136x; 1.0454x over previous
//
#include <hip/hip_runtime.h>
#include <cstdint>
#include <cstddef>

// Problem constants
#define CNU 500000      // item id offset
#define CB  65536       // batch
#define CE  128         // embedding dim
#define CF  172         // feature dim
#define EV  64          // events per block (4 M-tiles of 16)

typedef unsigned short ushort_t;
typedef __attribute__((ext_vector_type(8))) short b8;    // 8 x bf16
typedef __attribute__((ext_vector_type(4))) short b4;    // 4 x bf16
typedef __attribute__((ext_vector_type(4))) float f4;    // MFMA accumulator

#define MFMA16(a,b,c) __builtin_amdgcn_mfma_f32_16x16x32_bf16((a),(b),(c),0,0,0)

// ---- packed weight layout in ws (ushort elements), B-fragment order:
// frag(nt,kt): lane l holds B[k=kt*32+(l>>4)*8+j][n=nt*16+(l&15)], j=0..7
#define FRAG 512
#define U_KT 18                   // 14 k-tiles wih (K pad 448) + 4 whh
#define U_NT 24
#define U_SZ (U_NT*U_KT*FRAG)
#define PU_OFF 0
#define PI_OFF U_SZ
#define PG_OFF (2*U_SZ)
#define G_SZ (8*8*FRAG)
#define PP_OFF (PG_OFF + G_SZ)
#define P_SZ (8*4*FRAG)

// XOR-swizzle on 16B granules, both write and read sides (T2 discipline).
#define SWZ(r, c) ((c) ^ (((r) & 7) << 3))
#define AFRAG(T, r, c) (*(const b8*)&(T)[(r)][SWZ((r), (c))])

__device__ __forceinline__ ushort_t f2bf(float f) {
  unsigned u = __float_as_uint(f);
  return (ushort_t)((u + 0x7FFFu + ((u >> 16) & 1u)) >> 16);   // RNE
}
__device__ __forceinline__ float bf2f(ushort_t h) {
  return __uint_as_float(((unsigned)h) << 16);
}
__device__ __forceinline__ float sigmoid_(float x) { return 1.0f/(1.0f+__expf(-x)); }
__device__ __forceinline__ float tanh_(float x) { float e=__expf(2.0f*x); return 1.0f-2.0f/(e+1.0f); }

// ---- LDS: [EV][128] bf16 sub-tiles, 256B rows, XOR-swizzled.
// Tile reuse: QU hosts h'_u after pred is done; PU hosts h'_i after gi is done.
struct __align__(16) SLds {
  ushort_t PU[EV][128];   // proj_user  -> h'_i (after gi)
  ushort_t PI[EV][128];   // proj_item
  ushort_t FE[EV][192];   // features (cols 172-191 zero)
  ushort_t OU[EV][128];   // old_user (h_u)
  ushort_t OI[EV][128];   // old_item (h_i)
  ushort_t QU[EV][128];   // query_user -> h'_u (after pred)
};                        // 106,496 B -> 1 block/CU

extern "C" __global__ void prep_weights(
    const float* __restrict__ u_wih, const float* __restrict__ u_whh,
    const float* __restrict__ i_wih, const float* __restrict__ i_whh,
    const float* __restrict__ gate_w, const float* __restrict__ pred_w,
    ushort_t* __restrict__ ws)
{
  const int stride = gridDim.x * blockDim.x;
  const int tid = blockIdx.x * blockDim.x + threadIdx.x;
  for (int i = tid; i < U_SZ; i += stride) {
    const int nt = i / (U_KT*FRAG);
    const int r1 = i - nt*(U_KT*FRAG);
    const int kt = r1 / FRAG;
    const int e  = r1 - kt*FRAG;
    const int l  = e >> 3, j = e & 7;
    const int n  = nt*16 + (l & 15);
    const int k  = (l >> 4)*8 + j;
    float vu, vi;
    if (kt < 14) {
      const int kk = kt*32 + k;
      vu = (kk < 428) ? u_wih[(size_t)n*428 + kk] : 0.0f;
      vi = (kk < 428) ? i_wih[(size_t)n*428 + kk] : 0.0f;
    } else {
      const int kk = (kt - 14)*32 + k;
      vu = u_whh[(size_t)n*128 + kk];
      vi = i_whh[(size_t)n*128 + kk];
    }
    ws[PU_OFF + i] = f2bf(vu);
    ws[PI_OFF + i] = f2bf(vi);
  }
  for (int i = tid; i < G_SZ; i += stride) {
    const int nt = i / (8*FRAG);
    const int r1 = i - nt*(8*FRAG);
    const int kt = r1 / FRAG;
    const int e  = r1 - kt*FRAG;
    const int l  = e >> 3, j = e & 7;
    const int n  = nt*16 + (l & 15);
    const int kk = kt*32 + (l >> 4)*8 + j;
    ws[PG_OFF + i] = f2bf(gate_w[(size_t)n*256 + kk]);
  }
  for (int i = tid; i < P_SZ; i += stride) {
    const int nt = i / (4*FRAG);
    const int r1 = i - nt*(4*FRAG);
    const int kt = r1 / FRAG;
    const int e  = r1 - kt*FRAG;
    const int l  = e >> 3, j = e & 7;
    const int n  = nt*16 + (l & 15);
    const int kk = kt*32 + (l >> 4)*8 + j;
    ws[PP_OFF + i] = f2bf(pred_w[(size_t)n*128 + kk]);
  }
}

extern "C" __global__ void __launch_bounds__(512, 2)
jodie_main(const int* __restrict__ user_ids, const int* __restrict__ item_ids,
           const float* __restrict__ timestamps, const float* __restrict__ features,
           const int* __restrict__ query_time, const float* __restrict__ memv,
           const float* __restrict__ last_time, const float* __restrict__ time_w,
           const float* __restrict__ u_bih, const float* __restrict__ u_bhh,
           const float* __restrict__ i_bih, const float* __restrict__ i_bhh,
           const float* __restrict__ gate_b, const float* __restrict__ pred_b,
           const ushort_t* __restrict__ ws, float* __restrict__ d_out)
{
  __shared__ SLds s;
  const int t  = threadIdx.x;
  const int e0 = blockIdx.x * EV;

  // ---- stage: 16 threads/event, 8 cols each, 2 event-passes ----
  {
    const int c8 = (t & 15) * 8;
    const float qt = (float)query_time[0];
    const float4 tw0 = *(const float4*)&time_w[c8];
    const float4 tw1 = *(const float4*)&time_w[c8 + 4];
    const float twv[8] = {tw0.x,tw0.y,tw0.z,tw0.w, tw1.x,tw1.y,tw1.z,tw1.w};
#pragma unroll
    for (int ep = 0; ep < 2; ++ep) {
      const int e  = ep*32 + (t >> 4);
      const int ge = e0 + e;
      const int u   = user_ids[ge];
      const int itn = item_ids[ge] + CNU;
      const float ts = timestamps[ge];
      const float lu = last_time[u];
      const float li = last_time[itn];
      const float du = ts - lu, di = ts - li, dq = qt - lu;

      const float4 ou0 = *(const float4*)&memv[(size_t)u  *CE + c8];
      const float4 ou1 = *(const float4*)&memv[(size_t)u  *CE + c8 + 4];
      const float4 oi0 = *(const float4*)&memv[(size_t)itn*CE + c8];
      const float4 oi1 = *(const float4*)&memv[(size_t)itn*CE + c8 + 4];
      const float ouv[8] = {ou0.x,ou0.y,ou0.z,ou0.w, ou1.x,ou1.y,ou1.z,ou1.w};
      const float oiv[8] = {oi0.x,oi0.y,oi0.z,oi0.w, oi1.x,oi1.y,oi1.z,oi1.w};

      union { ushort_t u[8]; b8 v; } xu, xi, hu, hi, qv;
#pragma unroll
      for (int j = 0; j < 8; ++j) {
        xu.u[j] = f2bf(ouv[j] * (1.0f + du*twv[j]));
        xi.u[j] = f2bf(oiv[j] * (1.0f + di*twv[j]));
        hu.u[j] = f2bf(ouv[j]);
        hi.u[j] = f2bf(oiv[j]);
        qv.u[j] = f2bf(ouv[j] * (1.0f + dq*twv[j]));
      }
      *(b8*)&s.PU[e][SWZ(e, c8)] = xu.v;
      *(b8*)&s.PI[e][SWZ(e, c8)] = xi.v;
      *(b8*)&s.OU[e][SWZ(e, c8)] = hu.v;
      *(b8*)&s.OI[e][SWZ(e, c8)] = hi.v;
      *(b8*)&s.QU[e][SWZ(e, c8)] = qv.v;
    }
  }
  // ---- features: exact float4 tiling (172 = 43*4) ----
  for (int i = t; i < EV*43; i += 512) {
    const int e = i / 43, q = i - e*43;
    const float4 fv = *(const float4*)&features[(size_t)(e0 + e)*CF + q*4];
    union { ushort_t u[4]; b4 v; } fb;
    fb.u[0] = f2bf(fv.x); fb.u[1] = f2bf(fv.y);
    fb.u[2] = f2bf(fv.z); fb.u[3] = f2bf(fv.w);
    *(b4*)&s.FE[e][SWZ(e, q*4)] = fb.v;
  }
  for (int i = t; i < EV*20; i += 512) {
    const int e = i / 20, c = 172 + (i - e*20);
    s.FE[e][SWZ(e, c)] = 0;
  }
  __syncthreads();

  const int wv   = t >> 6, l = t & 63;
  const int lrow = l & 15;
  const int lk   = (l >> 4) * 8;
  const int col  = wv*16 + lrow;

  // ---- pred FIRST (reads QU; QU becomes h'_u storage afterwards) ----
  {
    const float bp = pred_b[col];
    f4 ap[4];
#pragma unroll
    for (int m = 0; m < 4; ++m) ap[m] = (f4){bp,bp,bp,bp};
    const ushort_t* WP = ws + PP_OFF + (size_t)wv*4*FRAG + l*8;
#pragma unroll
    for (int kt = 0; kt < 4; ++kt) {
      b8 fp = *(const b8*)(WP + (size_t)kt*FRAG);
#pragma unroll
      for (int m = 0; m < 4; ++m) {
        b8 a = AFRAG(s.QU, m*16 + lrow, 32*kt + lk);
        ap[m] = MFMA16(a, fp, ap[m]);
      }
    }
#pragma unroll
    for (int m = 0; m < 4; ++m)
#pragma unroll
      for (int r4 = 0; r4 < 4; ++r4) {
        const int row = m*16 + (l >> 4)*4 + r4;
        d_out[(size_t)(e0 + row)*CE + col] = ap[m][r4];
      }
  }
  __syncthreads();   // all pred reads of QU done

  // ---- biases ----
  const float bru = u_bih[col]     + u_bhh[col];
  const float bzu = u_bih[col+128] + u_bhh[col+128];
  const float bnu = u_bih[col+256];
  const float bhu = u_bhh[col+256];
  const float bri = i_bih[col]     + i_bhh[col];
  const float bzi = i_bih[col+128] + i_bhh[col+128];
  const float bni = i_bih[col+256];
  const float bhi = i_bhh[col+256];

  f4 aru[4], azu[4], anu[4], ari[4], azi[4], ani[4];
#pragma unroll
  for (int m = 0; m < 4; ++m) {
    aru[m] = (f4){bru,bru,bru,bru};  azu[m] = (f4){bzu,bzu,bzu,bzu};
    anu[m] = (f4){bnu,bnu,bnu,bnu};  ari[m] = (f4){bri,bri,bri,bri};
    azi[m] = (f4){bzi,bzi,bzi,bzi};  ani[m] = (f4){bni,bni,bni,bni};
  }

  const ushort_t* Wru = ws + PU_OFF + (size_t)(wv     )*U_KT*FRAG + l*8;
  const ushort_t* Wzu = ws + PU_OFF + (size_t)(wv +  8)*U_KT*FRAG + l*8;
  const ushort_t* Wnu = ws + PU_OFF + (size_t)(wv + 16)*U_KT*FRAG + l*8;
  const ushort_t* Wri = ws + PI_OFF + (size_t)(wv     )*U_KT*FRAG + l*8;
  const ushort_t* Wzi = ws + PI_OFF + (size_t)(wv +  8)*U_KT*FRAG + l*8;
  const ushort_t* Wni = ws + PI_OFF + (size_t)(wv + 16)*U_KT*FRAG + l*8;

  // ---- FUSED gi: each A-fragment feeds user (kt=ktu) and item (kt=kti) ----
#define GI_STEP(TILE, pf, ktu, kti)                                          \
  {                                                                          \
    b8 a_[4];                                                                \
    _Pragma("unroll")                                                        \
    for (int m = 0; m < 4; ++m) a_[m] = AFRAG(TILE, m*16 + lrow, 32*(pf) + lk); \
    b8 fru = *(const b8*)(Wru + (size_t)(ktu)*FRAG);                         \
    b8 fzu = *(const b8*)(Wzu + (size_t)(ktu)*FRAG);                         \
    b8 fnu = *(const b8*)(Wnu + (size_t)(ktu)*FRAG);                         \
    b8 fri = *(const b8*)(Wri + (size_t)(kti)*FRAG);                         \
    b8 fzi = *(const b8*)(Wzi + (size_t)(kti)*FRAG);                         \
    b8 fni = *(const b8*)(Wni + (size_t)(kti)*FRAG);                         \
    _Pragma("unroll")                                                        \
    for (int m = 0; m < 4; ++m) {                                            \
      aru[m] = MFMA16(a_[m], fru, aru[m]);                                   \
      azu[m] = MFMA16(a_[m], fzu, azu[m]);                                   \
      anu[m] = MFMA16(a_[m], fnu, anu[m]);                                   \
      ari[m] = MFMA16(a_[m], fri, ari[m]);                                   \
      azi[m] = MFMA16(a_[m], fzi, azi[m]);                                   \
      ani[m] = MFMA16(a_[m], fni, ani[m]);                                   \
    }                                                                        \
  }

#pragma unroll
  for (int pf = 0; pf < 4; ++pf) GI_STEP(s.PU, pf, pf, pf + 4)     // pu: user k0-127, item k128-255
#pragma unroll
  for (int pf = 0; pf < 4; ++pf) GI_STEP(s.PI, pf, pf + 4, pf)     // pi: user k128-255, item k0-127
#pragma unroll
  for (int pf = 0; pf < 6; ++pf) GI_STEP(s.FE, pf, pf + 8, pf + 8) // feat
#undef GI_STEP

  // ---- user gh (K=128) + elementwise -> h'_u into QU space ----
  {
    f4 ah[4];
#pragma unroll
    for (int m = 0; m < 4; ++m) ah[m] = (f4){bhu,bhu,bhu,bhu};
#pragma unroll
    for (int kt = 0; kt < 4; ++kt) {
      b8 fr = *(const b8*)(Wru + (size_t)(14+kt)*FRAG);
      b8 fz = *(const b8*)(Wzu + (size_t)(14+kt)*FRAG);
      b8 fn = *(const b8*)(Wnu + (size_t)(14+kt)*FRAG);
#pragma unroll
      for (int m = 0; m < 4; ++m) {
        b8 h = AFRAG(s.OU, m*16 + lrow, 32*kt + lk);
        aru[m] = MFMA16(h, fr, aru[m]);
        azu[m] = MFMA16(h, fz, azu[m]);
        ah[m]  = MFMA16(h, fn, ah[m]);
      }
    }
#pragma unroll
    for (int m = 0; m < 4; ++m)
#pragma unroll
      for (int r4 = 0; r4 < 4; ++r4) {
        const int row = m*16 + (l >> 4)*4 + r4;
        const float rr = sigmoid_(aru[m][r4]);
        const float zz = sigmoid_(azu[m][r4]);
        const float nn = tanh_(anu[m][r4] + rr*ah[m][r4]);
        const float h  = bf2f(s.OU[row][SWZ(row, col)]);
        s.QU[row][SWZ(row, col)] = f2bf((1.0f - zz)*nn + zz*h);
      }
  }
  __syncthreads();   // all waves past gi (PU reads) and ew_u writes

  // ---- item gh + elementwise -> h'_i into PU space ----
  {
    f4 ah[4];
#pragma unroll
    for (int m = 0; m < 4; ++m) ah[m] = (f4){bhi,bhi,bhi,bhi};
#pragma unroll
    for (int kt = 0; kt < 4; ++kt) {
      b8 fr = *(const b8*)(Wri + (size_t)(14+kt)*FRAG);
      b8 fz = *(const b8*)(Wzi + (size_t)(14+kt)*FRAG);
      b8 fn = *(const b8*)(Wni + (size_t)(14+kt)*FRAG);
#pragma unroll
      for (int m = 0; m < 4; ++m) {
        b8 h = AFRAG(s.OI, m*16 + lrow, 32*kt + lk);
        ari[m] = MFMA16(h, fr, ari[m]);
        azi[m] = MFMA16(h, fz, azi[m]);
        ah[m]  = MFMA16(h, fn, ah[m]);
      }
    }
#pragma unroll
    for (int m = 0; m < 4; ++m)
#pragma unroll
      for (int r4 = 0; r4 < 4; ++r4) {
        const int row = m*16 + (l >> 4)*4 + r4;
        const float rr = sigmoid_(ari[m][r4]);
        const float zz = sigmoid_(azi[m][r4]);
        const float nn = tanh_(ani[m][r4] + rr*ah[m][r4]);
        const float h  = bf2f(s.OI[row][SWZ(row, col)]);
        s.PU[row][SWZ(row, col)] = f2bf((1.0f - zz)*nn + zz*h);
      }
  }
  __syncthreads();   // h'_u (QU) and h'_i (PU) visible to all waves

  // ---- memory gates: shared gate_w fragments, user+item A streams ----
  {
    const float gb = gate_b[col];
    f4 agu[4], agi[4];
#pragma unroll
    for (int m = 0; m < 4; ++m) { agu[m] = (f4){gb,gb,gb,gb}; agi[m] = agu[m]; }
    const ushort_t* WG = ws + PG_OFF + (size_t)wv*8*FRAG + l*8;
#pragma unroll
    for (int kt = 0; kt < 8; ++kt) {
      b8 fg = *(const b8*)(WG + (size_t)kt*FRAG);
#pragma unroll
      for (int m = 0; m < 4; ++m) {
        b8 au = (kt < 4) ? AFRAG(s.OU, m*16 + lrow, 32*kt + lk)
                         : AFRAG(s.QU, m*16 + lrow, 32*(kt-4) + lk);
        b8 ai = (kt < 4) ? AFRAG(s.OI, m*16 + lrow, 32*kt + lk)
                         : AFRAG(s.PU, m*16 + lrow, 32*(kt-4) + lk);
        agu[m] = MFMA16(au, fg, agu[m]);
        agi[m] = MFMA16(ai, fg, agi[m]);
      }
    }
    float* __restrict__ outu = d_out + (size_t)CB*CE;
    float* __restrict__ outi = d_out + (size_t)2*CB*CE;
#pragma unroll
    for (int m = 0; m < 4; ++m)
#pragma unroll
      for (int r4 = 0; r4 < 4; ++r4) {
        const int row = m*16 + (l >> 4)*4 + r4;
        const float gu = sigmoid_(agu[m][r4]);
        const float gi = sigmoid_(agi[m][r4]);
        const float hu  = bf2f(s.OU[row][SWZ(row, col)]);
        const float hpu = bf2f(s.QU[row][SWZ(row, col)]);
        const float hi  = bf2f(s.OI[row][SWZ(row, col)]);
        const float hpi = bf2f(s.PU[row][SWZ(row, col)]);
        outu[(size_t)(e0 + row)*CE + col] = gu*hpu + (1.0f - gu)*hu;
        outi[(size_t)(e0 + row)*CE + col] = gi*hpi + (1.0f - gi)*hi;
      }
  }
}

extern "C" void kernel_launch(void* const* d_in, const int* in_sizes, int n_in,
                              void* d_out, int out_size, void* d_ws, size_t ws_size,
                              hipStream_t stream) {
  const int*   user_ids   = (const int*)d_in[0];
  const int*   item_ids   = (const int*)d_in[1];
  const float* timestamps = (const float*)d_in[2];
  const float* features   = (const float*)d_in[3];
  const int*   query_time = (const int*)d_in[4];
  const float* memv       = (const float*)d_in[5];
  const float* last_time  = (const float*)d_in[6];
  const float* time_w     = (const float*)d_in[7];
  const float* u_wih = (const float*)d_in[8];
  const float* u_whh = (const float*)d_in[9];
  const float* u_bih = (const float*)d_in[10];
  const float* u_bhh = (const float*)d_in[11];
  const float* i_wih = (const float*)d_in[12];
  const float* i_whh = (const float*)d_in[13];
  const float* i_bih = (const float*)d_in[14];
  const float* i_bhh = (const float*)d_in[15];
  const float* gate_w = (const float*)d_in[16];
  const float* gate_b = (const float*)d_in[17];
  const float* pred_w = (const float*)d_in[18];
  const float* pred_b = (const float*)d_in[19];
  ushort_t* ws = (ushort_t*)d_ws;
  float* out = (float*)d_out;

  prep_weights<<<dim3(256), dim3(256), 0, stream>>>(u_wih, u_whh, i_wih, i_whh,
                                                    gate_w, pred_w, ws);
  jodie_main<<<dim3(CB/EV), dim3(512), 0, stream>>>(user_ids, item_ids, timestamps,
                                                    features, query_time, memv,
                                                    last_time, time_w,
                                                    u_bih, u_bhh, i_bih, i_bhh,
                                                    gate_b, pred_b, ws, out);
}